// Round 17
// baseline (433.308 us; speedup 1.0000x reference)
//
#include <hip/hip_runtime.h>
#include <math.h>

// Problem constants (from reference setup_inputs)
#define BB 512
#define HH 512
#define RR 2048
#define CC 64
#define OUTD 202          // 3*64 + 2*3 + 4
// params workspace layout per batch (floats)
#define PSTRIDE 208
#define K_OFF 0
#define E_OFF 64
#define A_OFF 128
#define S_OFF 192         // 7 softmaxed shift weights
#define COMBO_OFF 199     // beta / k_n
#define G_OFF 200
#define GAMMA_OFF 201

#define PART_STRIDE 224   // padded 202, per (batch, hq) partial row

typedef float f32x4 __attribute__((ext_vector_type(4)));

__device__ __forceinline__ float softplusf_(float x) {
    return (x > 20.f) ? x : log1pf(expf(x));
}
__device__ __forceinline__ float sigmoidf_(float x) {
    return 1.f / (1.f + expf(-x));
}

// ---------------------------------------------------------------------------
// Kernel A1: split-K partial GEMM (proven R11). 256 blocks = 64 bg x 4 hq.
// ---------------------------------------------------------------------------
__global__ __launch_bounds__(256) void params_part_kernel(
    const float* __restrict__ h, const float* __restrict__ fc_w,
    float* __restrict__ part)
{
    __shared__ float h_sh[8][128];
    const int tid = threadIdx.x;
    const int bg = blockIdx.x >> 2;
    const int hq = blockIdx.x & 3;
    const int b0 = bg * 8;
    const int h0 = hq * 128;

    for (int idx = tid; idx < 8 * 128; idx += 256) {
        int j = idx >> 7, i = idx & 127;
        h_sh[j][i] = h[(size_t)(b0 + j) * HH + h0 + i];
    }
    __syncthreads();

    if (tid < OUTD) {
        float acc[8];
        #pragma unroll
        for (int j = 0; j < 8; ++j) acc[j] = 0.f;
        const float4* wr = (const float4*)(fc_w + (size_t)tid * HH + h0);
        #pragma unroll 4
        for (int i4 = 0; i4 < 32; ++i4) {
            float4 wv = wr[i4];
            int i = i4 * 4;
            #pragma unroll
            for (int j = 0; j < 8; ++j) {
                acc[j] = fmaf(wv.x, h_sh[j][i + 0], acc[j]);
                acc[j] = fmaf(wv.y, h_sh[j][i + 1], acc[j]);
                acc[j] = fmaf(wv.z, h_sh[j][i + 2], acc[j]);
                acc[j] = fmaf(wv.w, h_sh[j][i + 3], acc[j]);
            }
        }
        #pragma unroll
        for (int j = 0; j < 8; ++j) {
            part[((size_t)(b0 + j) * 4 + hq) * PART_STRIDE + tid] = acc[j];
        }
    }
}

// ---------------------------------------------------------------------------
// Kernel A2: combine partials + bias -> activations -> packed params (R11).
// ALSO zeroes the per-batch sync flags for the fused main kernel (runs
// before it in-stream every call, so flags are fresh on every graph replay).
// ---------------------------------------------------------------------------
__global__ __launch_bounds__(256) void params_combine_kernel(
    const float* __restrict__ part, const float* __restrict__ fc_b,
    float* __restrict__ pw, int* __restrict__ done1, int* __restrict__ done2)
{
    __shared__ float z_sh[80];
    const int b = blockIdx.x;
    const int tid = threadIdx.x;
    float* p = pw + (size_t)b * PSTRIDE;

    if (tid == 64) { done1[b] = 0; done2[b] = 0; }

    if (tid < OUTD) {
        const float* q = part + (size_t)b * 4 * PART_STRIDE + tid;
        float z = q[0] + q[PART_STRIDE] + q[2 * PART_STRIDE]
                + q[3 * PART_STRIDE] + fc_b[tid];
        if (tid < 74) z_sh[tid] = z;
        if (tid < 64)                      p[K_OFF + tid] = tanhf(z);
        else if (tid == 65)                p[G_OFF] = sigmoidf_(z);
        else if (tid == 73)                p[GAMMA_OFF] = softplusf_(z) + 1.f;
        else if (tid >= 74 && tid < 138)   p[E_OFF + (tid - 74)] = sigmoidf_(z);
        else if (tid >= 138)               p[A_OFF + (tid - 138)] = tanhf(z);
    }
    __syncthreads();

    if (tid < 64) {
        float kv = tanhf(z_sh[tid]);
        float ss = kv * kv;
        #pragma unroll
        for (int m = 1; m < 64; m <<= 1) ss += __shfl_xor(ss, m, 64);
        if (tid == 0) {
            float kn = fmaxf(sqrtf(ss), 1e-8f);
            float beta = softplusf_(z_sh[64]);
            p[COMBO_OFF] = beta / kn;
            float mx = -1e30f;
            #pragma unroll
            for (int q = 0; q < 7; ++q) mx = fmaxf(mx, z_sh[66 + q]);
            float ev[7], se = 0.f;
            #pragma unroll
            for (int q = 0; q < 7; ++q) {
                ev[q] = __expf(z_sh[66 + q] - mx);
                se += ev[q];
            }
            float inv = 1.f / se;
            #pragma unroll
            for (int q = 0; q < 7; ++q) p[S_OFF + q] = ev[q] * inv;
        }
    }
}

// ---------------------------------------------------------------------------
// 256-thread block reduce, fixed order -> deterministic
// ---------------------------------------------------------------------------
__device__ __forceinline__ float block_reduce_sum4(float v, float* red) {
    #pragma unroll
    for (int m = 1; m < 64; m <<= 1) v += __shfl_xor(v, m, 64);
    int wid = threadIdx.x >> 6;
    if ((threadIdx.x & 63) == 0) red[wid] = v;
    __syncthreads();
    float x = red[0] + red[1] + red[2] + red[3];
    __syncthreads();
    return x;
}

// ---------------------------------------------------------------------------
// per-batch 2-block handshake: publish (fence + int atomicAdd), then spin.
// Both blocks of a batch are guaranteed co-resident (grid 1024 at 4 blk/CU,
// LDS 8.3KB, VGPR<=128 via launch_bounds) -> no deadlock possible.
// Deterministic: float partials are plain-stored and summed in fixed order;
// only the int flag races.
// ---------------------------------------------------------------------------
__device__ __forceinline__ void pair_sync(int* flag) {
    __syncthreads();
    if (threadIdx.x == 0) {
        __threadfence();                       // release own partial
        atomicAdd(flag, 1);                    // device-scope int add
        while (__hip_atomic_load(flag, __ATOMIC_ACQUIRE,
                                 __HIP_MEMORY_SCOPE_AGENT) < 2)
            __builtin_amdgcn_s_sleep(4);
        __threadfence();                       // acquire partner's partial
    }
    __syncthreads();
}

// ---------------------------------------------------------------------------
// FUSED MAIN: grid 1024 x 256 (block = (batch, half), all co-resident).
// phase 1: score own 1024 rows (stream 256KB of memory, exp fused) -> sc,
//          esum partial -> pair_sync(done1[b])
// phase 2: gate(+-3 halo) -> conv -> pow own half in LDS -> psum partial
//          -> pair_sync(done2[b])
// phase 3: normalize; write out_w own half; update own 256KB slice
//          (self-L3-locality from phase 1).
// No kernel-boundary drains; batches desync so score/update of different
// batches overlap chip-wide.
// ---------------------------------------------------------------------------
__global__ __launch_bounds__(256, 4) void fused_main_kernel(
    const float* __restrict__ memory, const float* __restrict__ prev_w,
    const float* __restrict__ pw, float* __restrict__ sc,
    float* __restrict__ esum_part, float* __restrict__ psum_part,
    int* __restrict__ done1, int* __restrict__ done2,
    float* __restrict__ out_w, float* __restrict__ out_mem)
{
    __shared__ float wgs[1030];   // gate for rows rbase-3 .. rbase+1026
    __shared__ float wps[1024];   // pow values, own half
    __shared__ float red[4];

    const int tid = threadIdx.x;
    const int bid = blockIdx.x;
    const int b = bid >> 1;
    const int rbase = (bid & 1) * 1024;
    const float* p = pw + (size_t)b * PSTRIDE;
    const float* memb = memory + (size_t)b * RR * CC;

    // ---- phase 1: score own half ----
    {
        const int lane16 = tid & 15;
        const int rgrp = tid >> 4;            // 0..15
        const float4 k4 = *(const float4*)(p + K_OFF + lane16 * 4);
        const float combo = p[COMBO_OFF];
        float lsum = 0.f;
        #pragma unroll
        for (int mi = 0; mi < 8; ++mi) {
            float4 m4[8];
            #pragma unroll
            for (int j = 0; j < 8; ++j) {
                int r = rbase + (mi * 8 + j) * 16 + rgrp;
                m4[j] = *(const float4*)(memb + (size_t)r * CC + lane16 * 4);
            }
            #pragma unroll
            for (int j = 0; j < 8; ++j) {
                int r = rbase + (mi * 8 + j) * 16 + rgrp;
                float num = m4[j].x * k4.x + m4[j].y * k4.y + m4[j].z * k4.z
                          + m4[j].w * k4.w;
                float ssq = m4[j].x * m4[j].x + m4[j].y * m4[j].y
                          + m4[j].z * m4[j].z + m4[j].w * m4[j].w;
                #pragma unroll
                for (int m = 1; m < 16; m <<= 1) {
                    num += __shfl_xor(num, m, 64);
                    ssq += __shfl_xor(ssq, m, 64);
                }
                if (lane16 == 0) {
                    float mn = fmaxf(sqrtf(ssq), 1e-8f);
                    float ev = __expf(combo * num / mn);
                    sc[(size_t)b * RR + r] = ev;
                    lsum += ev;
                }
            }
        }
        float bs = block_reduce_sum4(lsum, red);
        if (tid == 0) esum_part[bid] = bs;
    }
    pair_sync(&done1[b]);

    // ---- phase 2: gate -> conv -> pow own half ----
    const float g = p[G_OFF];
    const float gamma = p[GAMMA_OFF];
    {
        const float s0 = p[S_OFF + 0], s1 = p[S_OFF + 1], s2 = p[S_OFF + 2],
                    s3 = p[S_OFF + 3], s4 = p[S_OFF + 4], s5 = p[S_OFF + 5],
                    s6 = p[S_OFF + 6];
        const float se = esum_part[2 * b] + esum_part[2 * b + 1];
        const float gi = g / se, omg = 1.f - g;
        const float* scb = sc + (size_t)b * RR;
        const float* pvb = prev_w + (size_t)b * RR;

        for (int idx = tid; idx < 1030; idx += 256) {
            int r = (rbase - 3 + idx) & (RR - 1);
            wgs[idx] = gi * scb[r] + omg * pvb[r];
        }
        __syncthreads();

        float lp = 0.f;
        #pragma unroll
        for (int t = 0; t < 4; ++t) {
            int idx = t * 256 + tid;
            float acc = s0 * wgs[idx]     + s1 * wgs[idx + 1]
                      + s2 * wgs[idx + 2] + s3 * wgs[idx + 3]
                      + s4 * wgs[idx + 4] + s5 * wgs[idx + 5]
                      + s6 * wgs[idx + 6];
            float v = __powf(acc, gamma);
            wps[idx] = v;
            lp += v;
        }
        float bs = block_reduce_sum4(lp, red);
        if (tid == 0) psum_part[bid] = bs;
    }
    pair_sync(&done2[b]);

    // ---- phase 3: normalize + out_w + memory update (self-local slice) ----
    {
        const float invp = 1.f /
            (psum_part[2 * b] + psum_part[2 * b + 1] + 1e-16f);

        // out_w own half: 4 values/thread
        {
            int l4 = tid * 4;
            float4 wv4 = make_float4(wps[l4] * invp, wps[l4 + 1] * invp,
                                     wps[l4 + 2] * invp, wps[l4 + 3] * invp);
            *(float4*)(out_w + (size_t)b * RR + rbase + l4) = wv4;
        }

        const int lane8 = tid & 7;
        const int rgrp = tid >> 3;            // 0..31
        const f32x4 ea = *(const f32x4*)(p + E_OFF + lane8 * 8);
        const f32x4 eb2 = *(const f32x4*)(p + E_OFF + lane8 * 8 + 4);
        const f32x4 aa = *(const f32x4*)(p + A_OFF + lane8 * 8);
        const f32x4 ab = *(const f32x4*)(p + A_OFF + lane8 * 8 + 4);
        float* omb = out_mem + (size_t)b * RR * CC;

        #pragma unroll
        for (int mi = 0; mi < 8; ++mi) {
            f32x4 ma[4], mb[4];
            float wv[4];
            #pragma unroll
            for (int j = 0; j < 4; ++j) {
                int r = rbase + (mi * 4 + j) * 32 + rgrp;
                const f32x4* mp =
                    (const f32x4*)(memb + (size_t)r * CC + lane8 * 8);
                ma[j] = mp[0];
                mb[j] = mp[1];
                wv[j] = wps[r - rbase] * invp;
            }
            #pragma unroll
            for (int j = 0; j < 4; ++j) {
                int r = rbase + (mi * 4 + j) * 32 + rgrp;
                f32x4 oa, ob;
                oa.x = ma[j].x * (1.f - wv[j] * ea.x) + wv[j] * aa.x;
                oa.y = ma[j].y * (1.f - wv[j] * ea.y) + wv[j] * aa.y;
                oa.z = ma[j].z * (1.f - wv[j] * ea.z) + wv[j] * aa.z;
                oa.w = ma[j].w * (1.f - wv[j] * ea.w) + wv[j] * aa.w;
                ob.x = mb[j].x * (1.f - wv[j] * eb2.x) + wv[j] * ab.x;
                ob.y = mb[j].y * (1.f - wv[j] * eb2.y) + wv[j] * ab.y;
                ob.z = mb[j].z * (1.f - wv[j] * eb2.z) + wv[j] * ab.z;
                ob.w = mb[j].w * (1.f - wv[j] * eb2.w) + wv[j] * ab.w;
                f32x4* op = (f32x4*)(omb + (size_t)r * CC + lane8 * 8);
                op[0] = oa;
                op[1] = ob;
            }
        }
    }
}

// ---------------------------------------------------------------------------
// Fallback kernels (R12 exact): score / weight / update.
// ---------------------------------------------------------------------------
__global__ __launch_bounds__(256) void score_kernel(
    const float* __restrict__ memory, const float* __restrict__ pw,
    float* __restrict__ sc, float* __restrict__ esum)
{
    __shared__ float red[4];
    const int tid = threadIdx.x;
    const int b = blockIdx.x >> 2;
    const int rbase = (blockIdx.x & 3) * 512;
    const int lane16 = tid & 15;
    const int rgrp = tid >> 4;
    const float* p = pw + (size_t)b * PSTRIDE;
    const float4 k4 = *(const float4*)(p + K_OFF + lane16 * 4);
    const float combo = p[COMBO_OFF];
    const float* memb = memory + (size_t)b * RR * CC;

    float lsum = 0.f;
    #pragma unroll 8
    for (int i = 0; i < 32; ++i) {
        int r = rbase + i * 16 + rgrp;
        float4 m4 = *(const float4*)(memb + (size_t)r * CC + lane16 * 4);
        float num = m4.x * k4.x + m4.y * k4.y + m4.z * k4.z + m4.w * k4.w;
        float ssq = m4.x * m4.x + m4.y * m4.y + m4.z * m4.z + m4.w * m4.w;
        #pragma unroll
        for (int m = 1; m < 16; m <<= 1) {
            num += __shfl_xor(num, m, 64);
            ssq += __shfl_xor(ssq, m, 64);
        }
        if (lane16 == 0) {
            float mn = fmaxf(sqrtf(ssq), 1e-8f);
            float ev = __expf(combo * num / mn);
            sc[(size_t)b * RR + r] = ev;
            lsum += ev;
        }
    }
    float bs = block_reduce_sum4(lsum, red);
    if (tid == 0) esum[blockIdx.x] = bs;
}

__global__ __launch_bounds__(256) void weight_kernel(
    const float* __restrict__ sc, const float* __restrict__ esum,
    const float* __restrict__ prev_w, const float* __restrict__ pw,
    float* __restrict__ out_w)
{
    __shared__ float buf[RR];
    __shared__ float wg[RR];
    __shared__ float red[4];
    const int b = blockIdx.x;
    const int tid = threadIdx.x;
    const float* p = pw + (size_t)b * PSTRIDE;
    const float g = p[G_OFF];
    const float gamma = p[GAMMA_OFF];
    const float s0 = p[S_OFF + 0], s1 = p[S_OFF + 1], s2 = p[S_OFF + 2],
                s3 = p[S_OFF + 3], s4 = p[S_OFF + 4], s5 = p[S_OFF + 5],
                s6 = p[S_OFF + 6];
    const float* eb = esum + (size_t)b * 4;
    const float se = eb[0] + eb[1] + eb[2] + eb[3];
    const float gi = g / se, omg = 1.f - g;

    #pragma unroll
    for (int t = 0; t < 4; ++t) {
        int r2 = (t * 256 + tid) * 2;
        float2 ev = *(const float2*)(sc + (size_t)b * RR + r2);
        float2 pv = *(const float2*)(prev_w + (size_t)b * RR + r2);
        wg[r2]     = gi * ev.x + omg * pv.x;
        wg[r2 + 1] = gi * ev.y + omg * pv.y;
    }
    __syncthreads();

    float lp = 0.f;
    #pragma unroll
    for (int t = 0; t < 8; ++t) {
        int r = t * 256 + tid;
        float acc = s0 * wg[(r - 3) & (RR - 1)]
                  + s1 * wg[(r - 2) & (RR - 1)]
                  + s2 * wg[(r - 1) & (RR - 1)]
                  + s3 * wg[r]
                  + s4 * wg[(r + 1) & (RR - 1)]
                  + s5 * wg[(r + 2) & (RR - 1)]
                  + s6 * wg[(r + 3) & (RR - 1)];
        float v = __powf(acc, gamma);
        buf[r] = v;
        lp += v;
    }
    const float ps = block_reduce_sum4(lp, red);
    const float invp = 1.f / (ps + 1e-16f);

    #pragma unroll
    for (int t = 0; t < 4; ++t) {
        int r2 = (t * 256 + tid) * 2;
        *(float2*)(out_w + (size_t)b * RR + r2) =
            make_float2(buf[r2] * invp, buf[r2 + 1] * invp);
    }
}

__global__ __launch_bounds__(256) void update_kernel(
    const float* __restrict__ memory, const float* __restrict__ w,
    const float* __restrict__ pw, float* __restrict__ out_mem)
{
    const int bid = (int)gridDim.x - 1 - (int)blockIdx.x;
    const int b = bid >> 2;
    const int rbase = (bid & 3) * 512;
    const int tid = threadIdx.x;
    const int lane8 = tid & 7;
    const int rgrp = tid >> 3;
    const float* p = pw + (size_t)b * PSTRIDE;
    const f32x4 ea = *(const f32x4*)(p + E_OFF + lane8 * 8);
    const f32x4 eb2 = *(const f32x4*)(p + E_OFF + lane8 * 8 + 4);
    const f32x4 aa = *(const f32x4*)(p + A_OFF + lane8 * 8);
    const f32x4 ab = *(const f32x4*)(p + A_OFF + lane8 * 8 + 4);
    const float* memb = memory + (size_t)b * RR * CC;
    float* omb = out_mem + (size_t)b * RR * CC;
    const float* wb = w + (size_t)b * RR;

    #pragma unroll
    for (int mi = 0; mi < 4; ++mi) {
        f32x4 ma[4], mb[4];
        float wv[4];
        #pragma unroll
        for (int j = 0; j < 4; ++j) {
            int r = rbase + (mi * 4 + j) * 32 + rgrp;
            const f32x4* mp = (const f32x4*)(memb + (size_t)r * CC + lane8 * 8);
            ma[j] = mp[0];
            mb[j] = mp[1];
            wv[j] = wb[r];
        }
        #pragma unroll
        for (int j = 0; j < 4; ++j) {
            int r = rbase + (mi * 4 + j) * 32 + rgrp;
            f32x4 oa, ob;
            oa.x = ma[j].x * (1.f - wv[j] * ea.x) + wv[j] * aa.x;
            oa.y = ma[j].y * (1.f - wv[j] * ea.y) + wv[j] * aa.y;
            oa.z = ma[j].z * (1.f - wv[j] * ea.z) + wv[j] * aa.z;
            oa.w = ma[j].w * (1.f - wv[j] * ea.w) + wv[j] * aa.w;
            ob.x = mb[j].x * (1.f - wv[j] * eb2.x) + wv[j] * ab.x;
            ob.y = mb[j].y * (1.f - wv[j] * eb2.y) + wv[j] * ab.y;
            ob.z = mb[j].z * (1.f - wv[j] * eb2.z) + wv[j] * ab.z;
            ob.w = mb[j].w * (1.f - wv[j] * eb2.w) + wv[j] * ab.w;
            f32x4* op = (f32x4*)(omb + (size_t)r * CC + lane8 * 8);
            op[0] = oa;
            op[1] = ob;
        }
    }
}

extern "C" void kernel_launch(void* const* d_in, const int* in_sizes, int n_in,
                              void* d_out, int out_size, void* d_ws, size_t ws_size,
                              hipStream_t stream) {
    const float* h      = (const float*)d_in[0];
    const float* prev_w = (const float*)d_in[1];
    const float* memory = (const float*)d_in[2];
    const float* fc_w   = (const float*)d_in[3];
    const float* fc_b   = (const float*)d_in[4];

    float* pw      = (float*)d_ws;              // 512*208 floats
    float* out_w   = (float*)d_out;             // B*R
    float* out_mem = out_w + (size_t)BB * RR;   // B*R*C

    const size_t pw_f   = (size_t)BB * PSTRIDE;
    const size_t br_f   = (size_t)BB * RR;
    const size_t ep_f   = (size_t)BB * 2;       // esum_part (one per half)
    const size_t pp_f   = (size_t)BB * 2;       // psum_part
    const size_t fl_f   = (size_t)BB;           // done1 (ints, 4B each)
    const size_t part_f = (size_t)BB * 4 * PART_STRIDE;
    const size_t need_f = pw_f + br_f + ep_f + pp_f + 2 * fl_f + part_f;

    float* sc        = pw + pw_f;
    float* esum_part = sc + br_f;
    float* psum_part = esum_part + ep_f;
    int*   done1     = (int*)(psum_part + pp_f);
    int*   done2     = done1 + BB;
    float* part      = (float*)(done2 + BB);

    if (ws_size >= need_f * sizeof(float)) {
        params_part_kernel<<<256, 256, 0, stream>>>(h, fc_w, part);
        params_combine_kernel<<<BB, 256, 0, stream>>>(part, fc_b, pw,
                                                      done1, done2);
        fused_main_kernel<<<BB * 2, 256, 0, stream>>>(
            memory, prev_w, pw, sc, esum_part, psum_part, done1, done2,
            out_w, out_mem);
    } else {
        // fallback: R12 5-kernel path, sc aliased onto out_mem (fully read
        // by weight before update overwrites; ordered by kernel boundaries).
        float* sc_fb   = out_mem;
        float* esum_fb = pw + pw_f;
        float* part_fb = esum_fb + (size_t)BB * 4;
        params_part_kernel<<<256, 256, 0, stream>>>(h, fc_w, part_fb);
        params_combine_kernel<<<BB, 256, 0, stream>>>(part_fb, fc_b, pw,
                                                      (int*)(esum_fb + BB * 4),
                                                      (int*)(esum_fb + BB * 4) + BB);
        score_kernel<<<BB * 4, 256, 0, stream>>>(memory, pw, sc_fb, esum_fb);
        weight_kernel<<<BB, 256, 0, stream>>>(sc_fb, esum_fb, prev_w, pw, out_w);
        update_kernel<<<BB * 4, 256, 0, stream>>>(memory, out_w, pw, out_mem);
    }
}

// Round 18
// 188.633 us; speedup vs baseline: 2.2971x; 2.2971x over previous
//
#include <hip/hip_runtime.h>
#include <math.h>

// Problem constants (from reference setup_inputs)
#define BB 512
#define HH 512
#define RR 2048
#define CC 64
#define OUTD 202          // 3*64 + 2*3 + 4
// params workspace layout per batch (floats)
#define PSTRIDE 208
#define K_OFF 0
#define E_OFF 64
#define A_OFF 128
#define S_OFF 192         // 7 softmaxed shift weights
#define COMBO_OFF 199     // beta / k_n
#define G_OFF 200
#define GAMMA_OFF 201

#define PART_STRIDE 224   // padded 202, per (batch, hq) partial row

typedef float f32x4 __attribute__((ext_vector_type(4)));

__device__ __forceinline__ float softplusf_(float x) {
    return (x > 20.f) ? x : log1pf(expf(x));
}
__device__ __forceinline__ float sigmoidf_(float x) {
    return 1.f / (1.f + expf(-x));
}

// ---------------------------------------------------------------------------
// Kernel A1: split-K partial GEMM (proven R11). 256 blocks = 64 bg x 4 hq.
// ---------------------------------------------------------------------------
__global__ __launch_bounds__(256) void params_part_kernel(
    const float* __restrict__ h, const float* __restrict__ fc_w,
    float* __restrict__ part)
{
    __shared__ float h_sh[8][128];
    const int tid = threadIdx.x;
    const int bg = blockIdx.x >> 2;
    const int hq = blockIdx.x & 3;
    const int b0 = bg * 8;
    const int h0 = hq * 128;

    for (int idx = tid; idx < 8 * 128; idx += 256) {
        int j = idx >> 7, i = idx & 127;
        h_sh[j][i] = h[(size_t)(b0 + j) * HH + h0 + i];
    }
    __syncthreads();

    if (tid < OUTD) {
        float acc[8];
        #pragma unroll
        for (int j = 0; j < 8; ++j) acc[j] = 0.f;
        const float4* wr = (const float4*)(fc_w + (size_t)tid * HH + h0);
        #pragma unroll 4
        for (int i4 = 0; i4 < 32; ++i4) {
            float4 wv = wr[i4];
            int i = i4 * 4;
            #pragma unroll
            for (int j = 0; j < 8; ++j) {
                acc[j] = fmaf(wv.x, h_sh[j][i + 0], acc[j]);
                acc[j] = fmaf(wv.y, h_sh[j][i + 1], acc[j]);
                acc[j] = fmaf(wv.z, h_sh[j][i + 2], acc[j]);
                acc[j] = fmaf(wv.w, h_sh[j][i + 3], acc[j]);
            }
        }
        #pragma unroll
        for (int j = 0; j < 8; ++j) {
            part[((size_t)(b0 + j) * 4 + hq) * PART_STRIDE + tid] = acc[j];
        }
    }
}

// ---------------------------------------------------------------------------
// Kernel A2: combine partials + bias -> activations -> packed params (R11).
// ---------------------------------------------------------------------------
__global__ __launch_bounds__(256) void params_combine_kernel(
    const float* __restrict__ part, const float* __restrict__ fc_b,
    float* __restrict__ pw)
{
    __shared__ float z_sh[80];
    const int b = blockIdx.x;
    const int tid = threadIdx.x;
    float* p = pw + (size_t)b * PSTRIDE;

    if (tid < OUTD) {
        const float* q = part + (size_t)b * 4 * PART_STRIDE + tid;
        float z = q[0] + q[PART_STRIDE] + q[2 * PART_STRIDE]
                + q[3 * PART_STRIDE] + fc_b[tid];
        if (tid < 74) z_sh[tid] = z;
        if (tid < 64)                      p[K_OFF + tid] = tanhf(z);
        else if (tid == 65)                p[G_OFF] = sigmoidf_(z);
        else if (tid == 73)                p[GAMMA_OFF] = softplusf_(z) + 1.f;
        else if (tid >= 74 && tid < 138)   p[E_OFF + (tid - 74)] = sigmoidf_(z);
        else if (tid >= 138)               p[A_OFF + (tid - 138)] = tanhf(z);
    }
    __syncthreads();

    if (tid < 64) {
        float kv = tanhf(z_sh[tid]);
        float ss = kv * kv;
        #pragma unroll
        for (int m = 1; m < 64; m <<= 1) ss += __shfl_xor(ss, m, 64);
        if (tid == 0) {
            float kn = fmaxf(sqrtf(ss), 1e-8f);
            float beta = softplusf_(z_sh[64]);
            p[COMBO_OFF] = beta / kn;
            float mx = -1e30f;
            #pragma unroll
            for (int q = 0; q < 7; ++q) mx = fmaxf(mx, z_sh[66 + q]);
            float ev[7], se = 0.f;
            #pragma unroll
            for (int q = 0; q < 7; ++q) {
                ev[q] = __expf(z_sh[66 + q] - mx);
                se += ev[q];
            }
            float inv = 1.f / se;
            #pragma unroll
            for (int q = 0; q < 7; ++q) p[S_OFF + q] = ev[q] * inv;
        }
    }
}

// ---------------------------------------------------------------------------
// 256-thread block reduce, fixed order -> deterministic
// ---------------------------------------------------------------------------
__device__ __forceinline__ float block_reduce_sum4(float v, float* red) {
    #pragma unroll
    for (int m = 1; m < 64; m <<= 1) v += __shfl_xor(v, m, 64);
    int wid = threadIdx.x >> 6;
    if ((threadIdx.x & 63) == 0) red[wid] = v;
    __syncthreads();
    float x = red[0] + red[1] + red[2] + red[3];
    __syncthreads();
    return x;
}

// ---------------------------------------------------------------------------
// Kernel S (R12 exact): pure read streamer, 2048 x 256, 16 lanes/row,
// exp fused, per-(b,quarter) exp-sums -> esum. Max-free softmax is exact
// (|arg| <= beta, small).
// ---------------------------------------------------------------------------
__global__ __launch_bounds__(256) void score_kernel(
    const float* __restrict__ memory, const float* __restrict__ pw,
    float* __restrict__ sc, float* __restrict__ esum)
{
    __shared__ float red[4];
    const int tid = threadIdx.x;
    const int b = blockIdx.x >> 2;
    const int rbase = (blockIdx.x & 3) * 512;
    const int lane16 = tid & 15;
    const int rgrp = tid >> 4;            // 0..15
    const float* p = pw + (size_t)b * PSTRIDE;
    const float4 k4 = *(const float4*)(p + K_OFF + lane16 * 4);
    const float combo = p[COMBO_OFF];
    const float* memb = memory + (size_t)b * RR * CC;

    float lsum = 0.f;
    #pragma unroll 8
    for (int i = 0; i < 32; ++i) {
        int r = rbase + i * 16 + rgrp;
        float4 m4 = *(const float4*)(memb + (size_t)r * CC + lane16 * 4);
        float num = m4.x * k4.x + m4.y * k4.y + m4.z * k4.z + m4.w * k4.w;
        float ssq = m4.x * m4.x + m4.y * m4.y + m4.z * m4.z + m4.w * m4.w;
        #pragma unroll
        for (int m = 1; m < 16; m <<= 1) {
            num += __shfl_xor(num, m, 64);
            ssq += __shfl_xor(ssq, m, 64);
        }
        if (lane16 == 0) {
            float mn = fmaxf(sqrtf(ssq), 1e-8f);
            float ev = __expf(combo * num / mn);
            sc[(size_t)b * RR + r] = ev;
            lsum += ev;
        }
    }
    float bs = block_reduce_sum4(lsum, red);
    if (tid == 0) esum[blockIdx.x] = bs;
}

// ---------------------------------------------------------------------------
// Kernel W (R12 exact): per-batch weight pipeline, 512 x 256.
// sc/prev_w reads cache-warm; writes final w only to out_w.
// ---------------------------------------------------------------------------
__global__ __launch_bounds__(256) void weight_kernel(
    const float* __restrict__ sc, const float* __restrict__ esum,
    const float* __restrict__ prev_w, const float* __restrict__ pw,
    float* __restrict__ out_w)
{
    __shared__ float buf[RR];
    __shared__ float wg[RR];
    __shared__ float red[4];
    const int b = blockIdx.x;
    const int tid = threadIdx.x;
    const float* p = pw + (size_t)b * PSTRIDE;
    const float g = p[G_OFF];
    const float gamma = p[GAMMA_OFF];
    const float s0 = p[S_OFF + 0], s1 = p[S_OFF + 1], s2 = p[S_OFF + 2],
                s3 = p[S_OFF + 3], s4 = p[S_OFF + 4], s5 = p[S_OFF + 5],
                s6 = p[S_OFF + 6];
    const float* eb = esum + (size_t)b * 4;
    const float se = eb[0] + eb[1] + eb[2] + eb[3];
    const float gi = g / se, omg = 1.f - g;

    // gate: 8 rows/thread, float2 vector loads
    #pragma unroll
    for (int t = 0; t < 4; ++t) {
        int r2 = (t * 256 + tid) * 2;
        float2 ev = *(const float2*)(sc + (size_t)b * RR + r2);
        float2 pv = *(const float2*)(prev_w + (size_t)b * RR + r2);
        wg[r2]     = gi * ev.x + omg * pv.x;
        wg[r2 + 1] = gi * ev.y + omg * pv.y;
    }
    __syncthreads();

    // 7-tap circular conv + pow
    float lp = 0.f;
    #pragma unroll
    for (int t = 0; t < 8; ++t) {
        int r = t * 256 + tid;
        float acc = s0 * wg[(r - 3) & (RR - 1)]
                  + s1 * wg[(r - 2) & (RR - 1)]
                  + s2 * wg[(r - 1) & (RR - 1)]
                  + s3 * wg[r]
                  + s4 * wg[(r + 1) & (RR - 1)]
                  + s5 * wg[(r + 2) & (RR - 1)]
                  + s6 * wg[(r + 3) & (RR - 1)];
        float v = __powf(acc, gamma);
        buf[r] = v;
        lp += v;
    }
    const float ps = block_reduce_sum4(lp, red);   // barrier: conv reads done
    const float invp = 1.f / (ps + 1e-16f);

    #pragma unroll
    for (int t = 0; t < 4; ++t) {
        int r2 = (t * 256 + tid) * 2;
        *(float2*)(out_w + (size_t)b * RR + r2) =
            make_float2(buf[r2] * invp, buf[r2 + 1] * invp);
    }
}

// ---------------------------------------------------------------------------
// Kernel U (R12 exact): pure read+write streamer, 2048 x 256, no barriers,
// reverse block order. Plain loads (L3 hits on lines score allocated),
// PLAIN stores (NT = +50% WRITE_SIZE, proven R7 vs R8). 4-row batched loads.
// ---------------------------------------------------------------------------
__global__ __launch_bounds__(256) void update_kernel(
    const float* __restrict__ memory, const float* __restrict__ w,
    const float* __restrict__ pw, float* __restrict__ out_mem)
{
    const int bid = (int)gridDim.x - 1 - (int)blockIdx.x;
    const int b = bid >> 2;
    const int rbase = (bid & 3) * 512;
    const int tid = threadIdx.x;
    const int lane8 = tid & 7;
    const int rgrp = tid >> 3;            // 0..31
    const float* p = pw + (size_t)b * PSTRIDE;
    const f32x4 ea = *(const f32x4*)(p + E_OFF + lane8 * 8);
    const f32x4 eb2 = *(const f32x4*)(p + E_OFF + lane8 * 8 + 4);
    const f32x4 aa = *(const f32x4*)(p + A_OFF + lane8 * 8);
    const f32x4 ab = *(const f32x4*)(p + A_OFF + lane8 * 8 + 4);
    const float* memb = memory + (size_t)b * RR * CC;
    float* omb = out_mem + (size_t)b * RR * CC;
    const float* wb = w + (size_t)b * RR;

    #pragma unroll
    for (int mi = 0; mi < 4; ++mi) {
        f32x4 ma[4], mb[4];
        float wv[4];
        #pragma unroll
        for (int j = 0; j < 4; ++j) {
            int r = rbase + (mi * 4 + j) * 32 + rgrp;
            const f32x4* mp = (const f32x4*)(memb + (size_t)r * CC + lane8 * 8);
            ma[j] = mp[0];
            mb[j] = mp[1];
            wv[j] = wb[r];
        }
        #pragma unroll
        for (int j = 0; j < 4; ++j) {
            int r = rbase + (mi * 4 + j) * 32 + rgrp;
            f32x4 oa, ob;
            oa.x = ma[j].x * (1.f - wv[j] * ea.x) + wv[j] * aa.x;
            oa.y = ma[j].y * (1.f - wv[j] * ea.y) + wv[j] * aa.y;
            oa.z = ma[j].z * (1.f - wv[j] * ea.z) + wv[j] * aa.z;
            oa.w = ma[j].w * (1.f - wv[j] * ea.w) + wv[j] * aa.w;
            ob.x = mb[j].x * (1.f - wv[j] * eb2.x) + wv[j] * ab.x;
            ob.y = mb[j].y * (1.f - wv[j] * eb2.y) + wv[j] * ab.y;
            ob.z = mb[j].z * (1.f - wv[j] * eb2.z) + wv[j] * ab.z;
            ob.w = mb[j].w * (1.f - wv[j] * eb2.w) + wv[j] * ab.w;
            f32x4* op = (f32x4*)(omb + (size_t)r * CC + lane8 * 8);
            op[0] = oa;
            op[1] = ob;
        }
    }
}

extern "C" void kernel_launch(void* const* d_in, const int* in_sizes, int n_in,
                              void* d_out, int out_size, void* d_ws, size_t ws_size,
                              hipStream_t stream) {
    const float* h      = (const float*)d_in[0];
    const float* prev_w = (const float*)d_in[1];
    const float* memory = (const float*)d_in[2];
    const float* fc_w   = (const float*)d_in[3];
    const float* fc_b   = (const float*)d_in[4];

    float* pw      = (float*)d_ws;              // 512*208 floats
    float* out_w   = (float*)d_out;             // B*R
    float* out_mem = out_w + (size_t)BB * RR;   // B*R*C

    const size_t pw_f   = (size_t)BB * PSTRIDE;
    const size_t br_f   = (size_t)BB * RR;
    const size_t es_f   = (size_t)BB * 4;
    const size_t part_f = (size_t)BB * 4 * PART_STRIDE;
    const size_t need_f = pw_f + br_f + es_f + part_f;

    float* sc   = pw + pw_f;
    float* esum = sc + br_f;
    float* part = esum + es_f;

    if (ws_size >= need_f * sizeof(float)) {
        params_part_kernel<<<256, 256, 0, stream>>>(h, fc_w, part);
        params_combine_kernel<<<BB, 256, 0, stream>>>(part, fc_b, pw);
        score_kernel<<<BB * 4, 256, 0, stream>>>(memory, pw, sc, esum);
        weight_kernel<<<BB, 256, 0, stream>>>(sc, esum, prev_w, pw, out_w);
        update_kernel<<<BB * 4, 256, 0, stream>>>(memory, out_w, pw, out_mem);
    } else {
        // fallback (ws ~800 MB in practice; safe path anyway): sc aliased
        // onto out_mem head — fully read before update overwrites, ordered
        // by kernel boundaries.
        float* sc_fb   = out_mem;
        float* esum_fb = pw + pw_f;
        float* part_fb = esum_fb + es_f;
        params_part_kernel<<<256, 256, 0, stream>>>(h, fc_w, part_fb);
        params_combine_kernel<<<BB, 256, 0, stream>>>(part_fb, fc_b, pw);
        score_kernel<<<BB * 4, 256, 0, stream>>>(memory, pw, sc_fb, esum_fb);
        weight_kernel<<<BB, 256, 0, stream>>>(sc_fb, esum_fb, prev_w, pw, out_w);
        update_kernel<<<BB * 4, 256, 0, stream>>>(memory, out_w, pw, out_mem);
    }
}